// Round 1
// baseline (432.860 us; speedup 1.0000x reference)
//
#include <hip/hip_runtime.h>

// GRU: B=4096, T=120, I=64, H=128. Gate order r,z,n (PyTorch).
// One block = 16 batch rows, 512 threads = 8 waves, persistent over all T.
// This version computes the MFMA as W*h^T (swapped operands): lane owns
// 4 CONSECUTIVE gate columns of ONE batch row -> vectorized h write
// (ds_write_b64), vectorized out store (dwordx4), packed bf16 converts,
// and biases enter as the MFMA C-operand (no per-step acc init).
// h_lds is double-buffered -> ONE barrier per step, and the barrier is a
// raw s_barrier with lgkmcnt(0) only (no vmcnt drain of out-stores).

#define Bv 4096
#define Tv 120
#define Iv 64
#define Hv 128

typedef __attribute__((ext_vector_type(8))) short short8;
typedef __attribute__((ext_vector_type(4))) float floatx4;
typedef __attribute__((ext_vector_type(2))) unsigned uintx2;

#if __has_builtin(__builtin_amdgcn_exp2f)
#define EXP2F(x) __builtin_amdgcn_exp2f(x)
#else
#define EXP2F(x) exp2f(x)
#endif
#if __has_builtin(__builtin_amdgcn_rcpf)
#define RCPF(x) __builtin_amdgcn_rcpf(x)
#else
#define RCPF(x) (1.0f / (x))
#endif

__device__ inline short f2bf(float f) {
    union { float f; unsigned u; } v; v.f = f;
    unsigned r = v.u + 0x7FFFu + ((v.u >> 16) & 1u);  // RNE
    return (short)(r >> 16);
}

// packed f32x2 -> bf16x2 (RNE), single VALU op
__device__ inline unsigned cvt_pk_bf16(float a, float b) {
    unsigned d;
    asm("v_cvt_pk_bf16_f32 %0, %1, %2" : "=v"(d) : "v"(a), "v"(b));
    return d;
}

__device__ inline float sigmoid_fast(float x) {
    return RCPF(1.0f + EXP2F(-1.44269504f * x));
}
__device__ inline float tanh_fast(float x) {
    return 1.0f - 2.0f * RCPF(1.0f + EXP2F(2.88539008f * x));
}

__launch_bounds__(512, 2)
__global__ void gru_persist(const float* __restrict__ x,
                            const float* __restrict__ W_ih,
                            const float* __restrict__ W_hh,
                            const float* __restrict__ b_ih,
                            const float* __restrict__ b_hh,
                            float* __restrict__ out) {
    constexpr int XSTR = 72;   // bf16 elems/row for x tile
    constexpr int HSTR = 136;  // bf16 elems/row for h tile
    __shared__ short h_lds[2][16 * HSTR];   // double-buffered h
    __shared__ short x_lds[2][16 * XSTR];

    const int tid  = threadIdx.x;
    const int wave = tid >> 6;       // 0..7
    const int lane = tid & 63;
    const int s    = lane & 15;      // A row (gate col in tile) / B col (batch row)
    const int quad = lane >> 4;      // 0..3
    const int b0   = blockIdx.x * 16;
    const int c    = wave * 16 + s;        // weight row for A-fragments
    const int cb   = wave * 16 + quad * 4; // this lane's 4 output gate cols

    // ---- biases as MFMA C-operand vectors (per-lane 4 consecutive cols) ----
    floatx4 bias_r  = *(const floatx4*)(b_ih + cb)       + *(const floatx4*)(b_hh + cb);
    floatx4 bias_z  = *(const floatx4*)(b_ih + 128 + cb) + *(const floatx4*)(b_hh + 128 + cb);
    floatx4 bias_xn = *(const floatx4*)(b_ih + 256 + cb);
    floatx4 bias_hn = *(const floatx4*)(b_hh + 256 + cb);

    // ---- preload weight A-fragments into registers (persist all T) ----
    // A-frag: lane holds W[16w + s][k], k = kst*32 + quad*8 + j
    short8 whh[3][4];
    short8 wih[3][2];
#pragma unroll
    for (int g = 0; g < 3; ++g) {
        const float* wr = W_hh + (size_t)(g * 128 + c) * 128;
#pragma unroll
        for (int kst = 0; kst < 4; ++kst) {
            const float* p = wr + kst * 32 + quad * 8;
            floatx4 lo = *(const floatx4*)p;
            floatx4 hi = *(const floatx4*)(p + 4);
            short8 f;
            f[0] = f2bf(lo[0]); f[1] = f2bf(lo[1]); f[2] = f2bf(lo[2]); f[3] = f2bf(lo[3]);
            f[4] = f2bf(hi[0]); f[5] = f2bf(hi[1]); f[6] = f2bf(hi[2]); f[7] = f2bf(hi[3]);
            whh[g][kst] = f;
        }
        const float* wi = W_ih + (size_t)(g * 128 + c) * 64;
#pragma unroll
        for (int kst = 0; kst < 2; ++kst) {
            const float* p = wi + kst * 32 + quad * 8;
            floatx4 lo = *(const floatx4*)p;
            floatx4 hi = *(const floatx4*)(p + 4);
            short8 f;
            f[0] = f2bf(lo[0]); f[1] = f2bf(lo[1]); f[2] = f2bf(lo[2]); f[3] = f2bf(lo[3]);
            f[4] = f2bf(hi[0]); f[5] = f2bf(hi[1]); f[6] = f2bf(hi[2]); f[7] = f2bf(hi[3]);
            wih[g][kst] = f;
        }
    }

    // ---- zero h_lds[0]; fp32 h carry; stage x[t=0] into x_lds[0] ----
    for (int i = tid; i < 16 * HSTR; i += 512) h_lds[0][i] = 0;
    floatx4 hcar = {0.f, 0.f, 0.f, 0.f};

    const int xrow = tid >> 5, xcp = tid & 31;   // 16 rows x 32 float2
    const float* xbase = x + ((size_t)(b0 + xrow) * Tv) * Iv + xcp * 2;
    {
        float2 v = *(const float2*)xbase;
        *(unsigned*)&x_lds[0][xrow * XSTR + xcp * 2] = cvt_pk_bf16(v.x, v.y);
    }
    __syncthreads();

    float* optr = out + ((size_t)(b0 + s) * Tv) * Hv + cb;   // row = batch, 4 cols
    float* hT   = out + (size_t)Bv * Tv * Hv;

#pragma unroll 2
    for (int t = 0; t < Tv; ++t) {
        const int hb = t & 1;
        // prefetch next x tile (global -> regs); clamp on last step (store unused)
        const int tn = (t + 1 < Tv) ? (t + 1) : t;
        float2 xv = *(const float2*)(xbase + (size_t)tn * Iv);

        // B-fragments: h row s (batch) over all k; x row s over k
        const short* hrow = &h_lds[hb][s * HSTR];
        short8 ah0 = *(const short8*)(hrow + quad * 8);
        short8 ah1 = *(const short8*)(hrow + 32 + quad * 8);
        short8 ah2 = *(const short8*)(hrow + 64 + quad * 8);
        short8 ah3 = *(const short8*)(hrow + 96 + quad * 8);
        const short* xr = &x_lds[hb][s * XSTR];
        short8 ax0 = *(const short8*)(xr + quad * 8);
        short8 ax1 = *(const short8*)(xr + 32 + quad * 8);

        // D = W * h^T (+ W_ih * x^T), biases ride in as C
        floatx4 accr  = __builtin_amdgcn_mfma_f32_16x16x32_bf16(whh[0][0], ah0, bias_r, 0, 0, 0);
        floatx4 accz  = __builtin_amdgcn_mfma_f32_16x16x32_bf16(whh[1][0], ah0, bias_z, 0, 0, 0);
        floatx4 acchn = __builtin_amdgcn_mfma_f32_16x16x32_bf16(whh[2][0], ah0, bias_hn, 0, 0, 0);
        accr  = __builtin_amdgcn_mfma_f32_16x16x32_bf16(whh[0][1], ah1, accr, 0, 0, 0);
        accz  = __builtin_amdgcn_mfma_f32_16x16x32_bf16(whh[1][1], ah1, accz, 0, 0, 0);
        acchn = __builtin_amdgcn_mfma_f32_16x16x32_bf16(whh[2][1], ah1, acchn, 0, 0, 0);
        accr  = __builtin_amdgcn_mfma_f32_16x16x32_bf16(whh[0][2], ah2, accr, 0, 0, 0);
        accz  = __builtin_amdgcn_mfma_f32_16x16x32_bf16(whh[1][2], ah2, accz, 0, 0, 0);
        acchn = __builtin_amdgcn_mfma_f32_16x16x32_bf16(whh[2][2], ah2, acchn, 0, 0, 0);
        accr  = __builtin_amdgcn_mfma_f32_16x16x32_bf16(whh[0][3], ah3, accr, 0, 0, 0);
        accz  = __builtin_amdgcn_mfma_f32_16x16x32_bf16(whh[1][3], ah3, accz, 0, 0, 0);
        acchn = __builtin_amdgcn_mfma_f32_16x16x32_bf16(whh[2][3], ah3, acchn, 0, 0, 0);

        floatx4 accxn = __builtin_amdgcn_mfma_f32_16x16x32_bf16(wih[2][0], ax0, bias_xn, 0, 0, 0);
        accr  = __builtin_amdgcn_mfma_f32_16x16x32_bf16(wih[0][0], ax0, accr, 0, 0, 0);
        accz  = __builtin_amdgcn_mfma_f32_16x16x32_bf16(wih[1][0], ax0, accz, 0, 0, 0);
        accxn = __builtin_amdgcn_mfma_f32_16x16x32_bf16(wih[2][1], ax1, accxn, 0, 0, 0);
        accr  = __builtin_amdgcn_mfma_f32_16x16x32_bf16(wih[0][1], ax1, accr, 0, 0, 0);
        accz  = __builtin_amdgcn_mfma_f32_16x16x32_bf16(wih[1][1], ax1, accz, 0, 0, 0);

        // gate math: lane owns batch row (b0+s), gate cols cb..cb+3
        floatx4 hv;
#pragma unroll
        for (int r = 0; r < 4; ++r) {
            float rg = sigmoid_fast(accr[r]);
            float zg = sigmoid_fast(accz[r]);
            float ng = tanh_fast(fmaf(rg, acchn[r], accxn[r]));
            float h  = fmaf(zg, hcar[r] - ng, ng);   // (1-z)*n + z*h
            hcar[r] = h;
            hv[r]   = h;
        }

        // stage prefetched x for t+1 (other buffer)
        *(unsigned*)&x_lds[hb ^ 1][xrow * XSTR + xcp * 2] = cvt_pk_bf16(xv.x, xv.y);

        // h -> bf16 packed, one 8B LDS write into the OTHER h buffer
        uintx2 hp;
        hp[0] = cvt_pk_bf16(hv[0], hv[1]);
        hp[1] = cvt_pk_bf16(hv[2], hv[3]);
        *(uintx2*)&h_lds[hb ^ 1][s * HSTR + cb] = hp;

        // out: one dwordx4 per lane (4 consecutive cols of one batch row)
        *(floatx4*)optr = hv;
        optr += Hv;

        // single barrier per step: wait LDS writes only; do NOT drain vmcnt
        asm volatile("s_waitcnt lgkmcnt(0)" ::: "memory");
        __builtin_amdgcn_s_barrier();
        asm volatile("" ::: "memory");
    }

    // final hidden state, one dwordx4 per lane
    *(floatx4*)(hT + (size_t)(b0 + s) * Hv + cb) = hcar;
}

extern "C" void kernel_launch(void* const* d_in, const int* in_sizes, int n_in,
                              void* d_out, int out_size, void* d_ws, size_t ws_size,
                              hipStream_t stream) {
    (void)in_sizes; (void)n_in; (void)out_size; (void)d_ws; (void)ws_size;
    const float* x    = (const float*)d_in[0];
    const float* W_ih = (const float*)d_in[1];
    const float* W_hh = (const float*)d_in[2];
    const float* b_ih = (const float*)d_in[3];
    const float* b_hh = (const float*)d_in[4];
    float* out = (float*)d_out;
    hipLaunchKernelGGL(gru_persist, dim3(Bv / 16), dim3(512), 0, stream,
                       x, W_ih, W_hh, b_ih, b_hh, out);
}

// Round 2
// 416.316 us; speedup vs baseline: 1.0397x; 1.0397x over previous
//
#include <hip/hip_runtime.h>

// GRU: B=4096, T=120, I=64, H=128. Gate order r,z,n (PyTorch).
// One block = 16 batch rows, 512 threads = 8 waves, persistent over all T.
// Schedule: the proven two-__syncthreads single-h-buffer loop (R0, 164us).
// Math layout: W*h^T swapped-operand MFMA (R1) -> lane owns 4 CONSECUTIVE
// gate columns of ONE batch row: h-write is one ds_write_b64, out-write is
// one global_store_dwordx4, converts are packed v_cvt_pk_bf16_f32, and
// biases enter as the MFMA C-operand (no per-step acc init movs).

#define Bv 4096
#define Tv 120
#define Iv 64
#define Hv 128

typedef __attribute__((ext_vector_type(8))) short short8;
typedef __attribute__((ext_vector_type(4))) float floatx4;
typedef __attribute__((ext_vector_type(2))) unsigned uintx2;

#if __has_builtin(__builtin_amdgcn_exp2f)
#define EXP2F(x) __builtin_amdgcn_exp2f(x)
#else
#define EXP2F(x) exp2f(x)
#endif
#if __has_builtin(__builtin_amdgcn_rcpf)
#define RCPF(x) __builtin_amdgcn_rcpf(x)
#else
#define RCPF(x) (1.0f / (x))
#endif

__device__ inline short f2bf(float f) {
    union { float f; unsigned u; } v; v.f = f;
    unsigned r = v.u + 0x7FFFu + ((v.u >> 16) & 1u);  // RNE
    return (short)(r >> 16);
}

// packed f32x2 -> bf16x2 (RNE), single VALU op
__device__ inline unsigned cvt_pk_bf16(float a, float b) {
    unsigned d;
    asm("v_cvt_pk_bf16_f32 %0, %1, %2" : "=v"(d) : "v"(a), "v"(b));
    return d;
}

__device__ inline float sigmoid_fast(float x) {
    return RCPF(1.0f + EXP2F(-1.44269504f * x));
}
__device__ inline float tanh_fast(float x) {
    return 1.0f - 2.0f * RCPF(1.0f + EXP2F(2.88539008f * x));
}

__launch_bounds__(512, 2)
__global__ void gru_persist(const float* __restrict__ x,
                            const float* __restrict__ W_ih,
                            const float* __restrict__ W_hh,
                            const float* __restrict__ b_ih,
                            const float* __restrict__ b_hh,
                            float* __restrict__ out) {
    constexpr int XSTR = 72;   // bf16 elems/row for x tile
    constexpr int HSTR = 136;  // bf16 elems/row for h tile
    __shared__ short h_lds[16 * HSTR];      // single buffer (two barriers/step)
    __shared__ short x_lds[2][16 * XSTR];

    const int tid  = threadIdx.x;
    const int wave = tid >> 6;       // 0..7
    const int lane = tid & 63;
    const int s    = lane & 15;      // A row (weight row in tile) / B col (batch row)
    const int quad = lane >> 4;      // 0..3
    const int b0   = blockIdx.x * 16;
    const int c    = wave * 16 + s;        // weight row for A-fragments
    const int cb   = wave * 16 + quad * 4; // this lane's 4 output gate cols

    // ---- biases as MFMA C-operand vectors (per-lane 4 consecutive cols) ----
    floatx4 bias_r  = *(const floatx4*)(b_ih + cb)       + *(const floatx4*)(b_hh + cb);
    floatx4 bias_z  = *(const floatx4*)(b_ih + 128 + cb) + *(const floatx4*)(b_hh + 128 + cb);
    floatx4 bias_xn = *(const floatx4*)(b_ih + 256 + cb);
    floatx4 bias_hn = *(const floatx4*)(b_hh + 256 + cb);

    // ---- preload weight A-fragments into registers (persist all T) ----
    // A-frag: lane holds W[16w + s][k], k = kst*32 + quad*8 + j
    short8 whh[3][4];
    short8 wih[3][2];
#pragma unroll
    for (int g = 0; g < 3; ++g) {
        const float* wr = W_hh + (size_t)(g * 128 + c) * 128;
#pragma unroll
        for (int kst = 0; kst < 4; ++kst) {
            const float* p = wr + kst * 32 + quad * 8;
            floatx4 lo = *(const floatx4*)p;
            floatx4 hi = *(const floatx4*)(p + 4);
            short8 f;
            f[0] = f2bf(lo[0]); f[1] = f2bf(lo[1]); f[2] = f2bf(lo[2]); f[3] = f2bf(lo[3]);
            f[4] = f2bf(hi[0]); f[5] = f2bf(hi[1]); f[6] = f2bf(hi[2]); f[7] = f2bf(hi[3]);
            whh[g][kst] = f;
        }
        const float* wi = W_ih + (size_t)(g * 128 + c) * 64;
#pragma unroll
        for (int kst = 0; kst < 2; ++kst) {
            const float* p = wi + kst * 32 + quad * 8;
            floatx4 lo = *(const floatx4*)p;
            floatx4 hi = *(const floatx4*)(p + 4);
            short8 f;
            f[0] = f2bf(lo[0]); f[1] = f2bf(lo[1]); f[2] = f2bf(lo[2]); f[3] = f2bf(lo[3]);
            f[4] = f2bf(hi[0]); f[5] = f2bf(hi[1]); f[6] = f2bf(hi[2]); f[7] = f2bf(hi[3]);
            wih[g][kst] = f;
        }
    }

    // ---- zero h_lds; fp32 h carry; stage x[t=0] into x_lds[0] ----
    for (int i = tid; i < 16 * HSTR; i += 512) h_lds[i] = 0;
    floatx4 hcar = {0.f, 0.f, 0.f, 0.f};

    const int xrow = tid >> 5, xcp = tid & 31;   // 16 rows x 32 float2
    const float* xbase = x + ((size_t)(b0 + xrow) * Tv) * Iv + xcp * 2;
    {
        float2 v = *(const float2*)xbase;
        *(unsigned*)&x_lds[0][xrow * XSTR + xcp * 2] = cvt_pk_bf16(v.x, v.y);
    }
    __syncthreads();

    float* optr = out + ((size_t)(b0 + s) * Tv) * Hv + cb;   // row = batch, 4 cols
    float* hT   = out + (size_t)Bv * Tv * Hv;

#pragma unroll 1
    for (int t = 0; t < Tv; ++t) {
        // prefetch next x tile (global -> regs), hides HBM latency behind compute
        float2 xv;
        if (t + 1 < Tv) xv = *(const float2*)(xbase + (size_t)(t + 1) * Iv);

        // B-fragments: h row s (batch) over all k; x row s over k
        const short* hrow = &h_lds[s * HSTR];
        short8 ah0 = *(const short8*)(hrow + quad * 8);
        short8 ah1 = *(const short8*)(hrow + 32 + quad * 8);
        short8 ah2 = *(const short8*)(hrow + 64 + quad * 8);
        short8 ah3 = *(const short8*)(hrow + 96 + quad * 8);
        const short* xr = &x_lds[t & 1][s * XSTR];
        short8 ax0 = *(const short8*)(xr + quad * 8);
        short8 ax1 = *(const short8*)(xr + 32 + quad * 8);

        // D = W * h^T (+ W_ih * x^T), biases ride in as C
        floatx4 accr  = __builtin_amdgcn_mfma_f32_16x16x32_bf16(whh[0][0], ah0, bias_r, 0, 0, 0);
        floatx4 accz  = __builtin_amdgcn_mfma_f32_16x16x32_bf16(whh[1][0], ah0, bias_z, 0, 0, 0);
        floatx4 acchn = __builtin_amdgcn_mfma_f32_16x16x32_bf16(whh[2][0], ah0, bias_hn, 0, 0, 0);
        accr  = __builtin_amdgcn_mfma_f32_16x16x32_bf16(whh[0][1], ah1, accr, 0, 0, 0);
        accz  = __builtin_amdgcn_mfma_f32_16x16x32_bf16(whh[1][1], ah1, accz, 0, 0, 0);
        acchn = __builtin_amdgcn_mfma_f32_16x16x32_bf16(whh[2][1], ah1, acchn, 0, 0, 0);
        accr  = __builtin_amdgcn_mfma_f32_16x16x32_bf16(whh[0][2], ah2, accr, 0, 0, 0);
        accz  = __builtin_amdgcn_mfma_f32_16x16x32_bf16(whh[1][2], ah2, accz, 0, 0, 0);
        acchn = __builtin_amdgcn_mfma_f32_16x16x32_bf16(whh[2][2], ah2, acchn, 0, 0, 0);
        accr  = __builtin_amdgcn_mfma_f32_16x16x32_bf16(whh[0][3], ah3, accr, 0, 0, 0);
        accz  = __builtin_amdgcn_mfma_f32_16x16x32_bf16(whh[1][3], ah3, accz, 0, 0, 0);
        acchn = __builtin_amdgcn_mfma_f32_16x16x32_bf16(whh[2][3], ah3, acchn, 0, 0, 0);

        floatx4 accxn = __builtin_amdgcn_mfma_f32_16x16x32_bf16(wih[2][0], ax0, bias_xn, 0, 0, 0);
        accr  = __builtin_amdgcn_mfma_f32_16x16x32_bf16(wih[0][0], ax0, accr, 0, 0, 0);
        accz  = __builtin_amdgcn_mfma_f32_16x16x32_bf16(wih[1][0], ax0, accz, 0, 0, 0);
        accxn = __builtin_amdgcn_mfma_f32_16x16x32_bf16(wih[2][1], ax1, accxn, 0, 0, 0);
        accr  = __builtin_amdgcn_mfma_f32_16x16x32_bf16(wih[0][1], ax1, accr, 0, 0, 0);
        accz  = __builtin_amdgcn_mfma_f32_16x16x32_bf16(wih[1][1], ax1, accz, 0, 0, 0);

        __syncthreads();  // all A/B-frag reads drained; safe to overwrite h_lds

        // gate math: lane owns batch row (b0+s), gate cols cb..cb+3
        floatx4 hv;
#pragma unroll
        for (int r = 0; r < 4; ++r) {
            float rg = sigmoid_fast(accr[r]);
            float zg = sigmoid_fast(accz[r]);
            float ng = tanh_fast(fmaf(rg, acchn[r], accxn[r]));
            float h  = fmaf(zg, hcar[r] - ng, ng);   // (1-z)*n + z*h
            hcar[r] = h;
            hv[r]   = h;
        }

        // h -> bf16 packed, one 8B LDS write (single buffer, barrier-protected)
        uintx2 hp;
        hp[0] = cvt_pk_bf16(hv[0], hv[1]);
        hp[1] = cvt_pk_bf16(hv[2], hv[3]);
        *(uintx2*)&h_lds[s * HSTR + cb] = hp;

        // out: one dwordx4 per lane (4 consecutive cols of one batch row)
        *(floatx4*)optr = hv;
        optr += Hv;

        // stage prefetched x for t+1
        if (t + 1 < Tv) {
            *(unsigned*)&x_lds[(t + 1) & 1][xrow * XSTR + xcp * 2] = cvt_pk_bf16(xv.x, xv.y);
        }

        __syncthreads();  // h_lds / x_lds ready for next step
    }

    // final hidden state, one dwordx4 per lane
    *(floatx4*)(hT + (size_t)(b0 + s) * Hv + cb) = hcar;
}

extern "C" void kernel_launch(void* const* d_in, const int* in_sizes, int n_in,
                              void* d_out, int out_size, void* d_ws, size_t ws_size,
                              hipStream_t stream) {
    (void)in_sizes; (void)n_in; (void)out_size; (void)d_ws; (void)ws_size;
    const float* x    = (const float*)d_in[0];
    const float* W_ih = (const float*)d_in[1];
    const float* W_hh = (const float*)d_in[2];
    const float* b_ih = (const float*)d_in[3];
    const float* b_hh = (const float*)d_in[4];
    float* out = (float*)d_out;
    hipLaunchKernelGGL(gru_persist, dim3(Bv / 16), dim3(512), 0, stream,
                       x, W_ih, W_hh, b_ih, b_hh, out);
}